// Round 1
// baseline (205.283 us; speedup 1.0000x reference)
//
#include <hip/hip_runtime.h>

// HTMM: B_TREES=8, ARITY=4, DEPTH=8, C=8, M=100, NGEN=4
// COUNTS[l] = 8*4^l ; OFFS = cumsum
constexpr int OFFS[10] = {0, 8, 40, 168, 680, 2728, 10920, 43688, 174760, 699048};

// lane mapping within a 32-lane group: r = g*8 + s  (g = gen, s = state)
// Table layouts in workspace (all float):
//   WTD[(j*8+d)*32 + g*8+s] = smA_t[j][s][d][g]   (child-state s | parent d, pos j)
//   WUP[(j*8+c)*32 + g*8+d] = smA_t[j][c][d][g]
//   EMT[m*32 + g*8+c]       = smB[c][m][g]
//   PIT[g*8+c]              = smPi[c][g]

// Recompute prior of node `nd` at level LV by walking the root path.
// 32-lane group cooperative; cross-lane via shfl (intra-wave, barrier-free).
template <int LV>
static __device__ __forceinline__ float prior_path(int nd,
                                                   const float* __restrict__ wtd_l,
                                                   const float* __restrict__ PIT,
                                                   int g, int s) {
  float v = PIT[g * 8 + s];
#pragma unroll
  for (int k = 1; k <= LV; k++) {
    int j = (nd >> (2 * (LV - k))) & 3;  // position of level-k ancestor
    float pv[8];
#pragma unroll
    for (int d = 0; d < 8; d++) pv[d] = __shfl(v, g * 8 + d, 32);
    float nv = 0.f;
#pragma unroll
    for (int d = 0; d < 8; d++) nv += wtd_l[((j * 8 + d) * 4 + g) * 8 + s] * pv[d];
    v = nv;
  }
  return v;
}

static __device__ __forceinline__ float bfly8(float v) {
  v += __shfl_xor(v, 1);
  v += __shfl_xor(v, 2);
  v += __shfl_xor(v, 4);
  return v;  // sum over the 8 states in this lane's octet (all octet lanes get it)
}

// ---------------- k_prep: softmax tables ----------------
__global__ __launch_bounds__(256) void k_prep(const float* __restrict__ A,
                                              const float* __restrict__ Bm,
                                              const float* __restrict__ Pi,
                                              float* __restrict__ WTD,
                                              float* __restrict__ WUP,
                                              float* __restrict__ EMT,
                                              float* __restrict__ PIT) {
  int t = threadIdx.x;
  if (t < 128) {  // A: softmax over axis 0 (child state), column = (d,j,g)
    int d = t >> 4, j = (t >> 2) & 3, g = t & 3;
    float v[8], sum = 0.f;
#pragma unroll
    for (int s = 0; s < 8; s++) { v[s] = __expf(A[((s * 8 + d) * 4 + j) * 4 + g]); sum += v[s]; }
    float inv = 1.f / sum;
#pragma unroll
    for (int s = 0; s < 8; s++) {
      float p = v[s] * inv;
      WTD[((j * 8 + d) * 4 + g) * 8 + s] = p;
      WUP[((j * 8 + s) * 4 + g) * 8 + d] = p;
    }
  } else if (t < 160) {  // B: softmax over m, row = (c,g)
    int c = (t - 128) >> 2, g = (t - 128) & 3;
    float sum = 0.f;
    for (int m = 0; m < 100; m++) sum += __expf(Bm[(c * 100 + m) * 4 + g]);
    float inv = 1.f / sum;
    for (int m = 0; m < 100; m++) EMT[m * 32 + g * 8 + c] = __expf(Bm[(c * 100 + m) * 4 + g]) * inv;
  } else if (t < 164) {  // Pi: softmax over c
    int g = t - 160;
    float v[8], sum = 0.f;
#pragma unroll
    for (int s = 0; s < 8; s++) { v[s] = __expf(Pi[s * 4 + g]); sum += v[s]; }
    float inv = 1.f / sum;
#pragma unroll
    for (int s = 0; s < 8; s++) PIT[g * 8 + s] = v[s] * inv;
  }
}

// ---------------- k_sub6: fused level 6..8 subtrees ----------------
// grid 1024 x 256. Each 32-lane group handles 4 consecutive level-6 subtrees
// (root + 4 children + 16 leaves), entirely in registers + shuffles.
__global__ __launch_bounds__(256) void k_sub6(const int* __restrict__ x,
                                              const float* __restrict__ WTD,
                                              const float* __restrict__ WUP,
                                              const float* __restrict__ EMT,
                                              const float* __restrict__ PIT,
                                              float* __restrict__ RAT6,
                                              float* __restrict__ out) {
  __shared__ __align__(16) float wtd_l[1024];
  __shared__ __align__(16) float wup_l[1024];
  __shared__ __align__(16) float emt_l[3200];
  __shared__ float llb[4];
  int t = threadIdx.x;
  for (int i = t; i < 1024; i += 256) { wtd_l[i] = WTD[i]; wup_l[i] = WUP[i]; }
  for (int i = t; i < 3200; i += 256) emt_l[i] = EMT[i];
  if (t < 4) llb[t] = 0.f;
  __syncthreads();

  int r = t & 31, g = r >> 3, s = r & 7, grp = t >> 5;
  float wtd_r[4][8], wup_r[4][8];
#pragma unroll
  for (int j = 0; j < 4; j++)
#pragma unroll
    for (int d = 0; d < 8; d++) {
      wtd_r[j][d] = wtd_l[(j * 8 + d) * 32 + r];
      wup_r[j][d] = wup_l[(j * 8 + d) * 32 + r];
    }

  float acc = 0.f;
  for (int k = 0; k < 4; k++) {
    int p6 = (blockIdx.x * 8 + grp) * 4 + k;
    // root prior via path from tree root (6 matvecs)
    float v0 = prior_path<6>(p6, wtd_l, PIT, g, s);

    // top-down level 6->7 (priors u[0..3])
    float pv[8];
#pragma unroll
    for (int d = 0; d < 8; d++) pv[d] = __shfl(v0, g * 8 + d, 32);
    float u[4];
#pragma unroll
    for (int q = 0; q < 4; q++) {
      float uu = 0.f;
#pragma unroll
      for (int d = 0; d < 8; d++) uu += wtd_r[q][d] * pv[d];
      u[q] = uu;
    }
    // top-down level 7->8 (leaf priors w[0..15])
    float w[16];
#pragma unroll
    for (int q = 0; q < 4; q++) {
#pragma unroll
      for (int d = 0; d < 8; d++) pv[d] = __shfl(u[q], g * 8 + d, 32);
#pragma unroll
      for (int j = 0; j < 4; j++) {
        float uu = 0.f;
#pragma unroll
        for (int d = 0; d < 8; d++) uu += wtd_r[j][d] * pv[d];
        w[4 * q + j] = uu;
      }
    }
    // upward: leaves (level 8).  ratio = em/nu, nu = sum_c prior*em
    int xb8 = OFFS[8] + 16 * p6;
#pragma unroll
    for (int idx = 0; idx < 16; idx++) {
      int xg = x[xb8 + idx];
      float em = emt_l[xg * 32 + r];
      float nu = bfly8(w[idx] * em);
      w[idx] = em / nu;
      acc += __logf(nu);
    }
    // upward: level 7 nodes
    int xb7 = OFFS[7] + 4 * p6;
#pragma unroll
    for (int q = 0; q < 4; q++) {
      float prod = 1.f;
#pragma unroll
      for (int j = 0; j < 4; j++) {
        float bu = 0.f;
#pragma unroll
        for (int c = 0; c < 8; c++) bu += wup_r[j][c] * __shfl(w[4 * q + j], g * 8 + c, 32);
        prod *= bu;
      }
      int xg = x[xb7 + q];
      float em = emt_l[xg * 32 + r];
      float nu = bfly8(u[q] * em * prod);
      u[q] = em * prod / nu;
      acc += __logf(nu);
    }
    // upward: subtree root (level 6) -> write RAT6
    {
      float prod = 1.f;
#pragma unroll
      for (int j = 0; j < 4; j++) {
        float bu = 0.f;
#pragma unroll
        for (int c = 0; c < 8; c++) bu += wup_r[j][c] * __shfl(u[j], g * 8 + c, 32);
        prod *= bu;
      }
      int xg = x[OFFS[6] + p6];
      float em = emt_l[xg * 32 + r];
      float nu = bfly8(v0 * em * prod);
      RAT6[p6 * 32 + r] = em * prod / nu;
      acc += __logf(nu);
    }
  }
  if (s == 0) atomicAdd(&llb[g], acc);
  __syncthreads();
  // block's 32 subtrees are within one tree (4096 subtrees/tree, 32 | 4096)
  if (t < 4) atomicAdd(&out[(blockIdx.x >> 7) * 4 + t], llb[t]);
}

// ---------------- k_up<L>: one upward level (L=5,4,3) ----------------
template <int L>
__global__ __launch_bounds__(256) void k_up(const int* __restrict__ x,
                                            const float* __restrict__ WTD,
                                            const float* __restrict__ WUP,
                                            const float* __restrict__ EMT,
                                            const float* __restrict__ PIT,
                                            const float* __restrict__ RATC,
                                            float* __restrict__ RATP,
                                            float* __restrict__ out) {
  __shared__ __align__(16) float wtd_l[1024];
  __shared__ __align__(16) float wup_l[1024];
  __shared__ __align__(16) float emt_l[3200];
  __shared__ float llb[4];
  int t = threadIdx.x;
  for (int i = t; i < 1024; i += 256) { wtd_l[i] = WTD[i]; wup_l[i] = WUP[i]; }
  for (int i = t; i < 3200; i += 256) emt_l[i] = EMT[i];
  if (t < 4) llb[t] = 0.f;
  __syncthreads();

  int r = t & 31, g = r >> 3, s = r & 7;
  float wup_r[4][8];
#pragma unroll
  for (int j = 0; j < 4; j++)
#pragma unroll
    for (int c = 0; c < 8; c++) wup_r[j][c] = wup_l[(j * 8 + c) * 32 + r];

  int n = (blockIdx.x * 256 + t) >> 5;  // node at level L
  float pr = prior_path<L>(n, wtd_l, PIT, g, s);
  float prod = 1.f;
#pragma unroll
  for (int j = 0; j < 4; j++) {
    const float4* rp = (const float4*)&RATC[(4 * n + j) * 32 + g * 8];
    float4 aa = rp[0], bb = rp[1];
    float bu = wup_r[j][0] * aa.x + wup_r[j][1] * aa.y + wup_r[j][2] * aa.z + wup_r[j][3] * aa.w +
               wup_r[j][4] * bb.x + wup_r[j][5] * bb.y + wup_r[j][6] * bb.z + wup_r[j][7] * bb.w;
    prod *= bu;
  }
  int xg = x[OFFS[L] + n];
  float em = emt_l[xg * 32 + r];
  float nu = bfly8(pr * em * prod);
  RATP[n * 32 + r] = em * prod / nu;
  if (s == 0) atomicAdd(&llb[g], __logf(nu));
  __syncthreads();
  if (t < 4) {
    int tree = (blockIdx.x * 8) >> (2 * L);  // 8 nodes/block, same tree
    atomicAdd(&out[tree * 4 + t], llb[t]);
  }
}

// ---------------- k_top: levels 2 -> 0, single block ----------------
__global__ __launch_bounds__(256) void k_top(const int* __restrict__ x,
                                             const float* __restrict__ WTD,
                                             const float* __restrict__ WUP,
                                             const float* __restrict__ EMT,
                                             const float* __restrict__ PIT,
                                             const float* __restrict__ RAT3,
                                             float* __restrict__ out) {
  __shared__ __align__(16) float wtd_l[1024];
  __shared__ __align__(16) float emt_l[3200];
  __shared__ __align__(16) float rat2_l[128 * 32];
  __shared__ __align__(16) float rat1_l[32 * 32];
  __shared__ float llb[32];
  int t = threadIdx.x;
  for (int i = t; i < 1024; i += 256) wtd_l[i] = WTD[i];
  for (int i = t; i < 3200; i += 256) emt_l[i] = EMT[i];
  if (t < 32) llb[t] = 0.f;
  int r = t & 31, g = r >> 3, s = r & 7, grp = t >> 5;
  float wup_r[4][8];
#pragma unroll
  for (int j = 0; j < 4; j++)
#pragma unroll
    for (int c = 0; c < 8; c++) wup_r[j][c] = WUP[(j * 8 + c) * 32 + r];
  __syncthreads();

  // level 2 (128 nodes), children ratios from RAT3 (global)
  for (int n = grp; n < 128; n += 8) {
    float pr = prior_path<2>(n, wtd_l, PIT, g, s);
    float prod = 1.f;
#pragma unroll
    for (int j = 0; j < 4; j++) {
      const float4* rp = (const float4*)&RAT3[(4 * n + j) * 32 + g * 8];
      float4 aa = rp[0], bb = rp[1];
      float bu = wup_r[j][0] * aa.x + wup_r[j][1] * aa.y + wup_r[j][2] * aa.z + wup_r[j][3] * aa.w +
                 wup_r[j][4] * bb.x + wup_r[j][5] * bb.y + wup_r[j][6] * bb.z + wup_r[j][7] * bb.w;
      prod *= bu;
    }
    int xg = x[OFFS[2] + n];
    float em = emt_l[xg * 32 + r];
    float nu = bfly8(pr * em * prod);
    rat2_l[n * 32 + r] = em * prod / nu;
    if (s == 0) atomicAdd(&llb[(n >> 4) * 4 + g], __logf(nu));
  }
  __syncthreads();
  // level 1 (32 nodes)
  for (int n = grp; n < 32; n += 8) {
    float pr = prior_path<1>(n, wtd_l, PIT, g, s);
    float prod = 1.f;
#pragma unroll
    for (int j = 0; j < 4; j++) {
      const float4* rp = (const float4*)&rat2_l[(4 * n + j) * 32 + g * 8];
      float4 aa = rp[0], bb = rp[1];
      float bu = wup_r[j][0] * aa.x + wup_r[j][1] * aa.y + wup_r[j][2] * aa.z + wup_r[j][3] * aa.w +
                 wup_r[j][4] * bb.x + wup_r[j][5] * bb.y + wup_r[j][6] * bb.z + wup_r[j][7] * bb.w;
      prod *= bu;
    }
    int xg = x[OFFS[1] + n];
    float em = emt_l[xg * 32 + r];
    float nu = bfly8(pr * em * prod);
    rat1_l[n * 32 + r] = em * prod / nu;
    if (s == 0) atomicAdd(&llb[(n >> 2) * 4 + g], __logf(nu));
  }
  __syncthreads();
  // level 0 (8 roots), n = grp; prior = smPi
  {
    int n = grp;
    float pr = PIT[g * 8 + s];
    float prod = 1.f;
#pragma unroll
    for (int j = 0; j < 4; j++) {
      const float4* rp = (const float4*)&rat1_l[(4 * n + j) * 32 + g * 8];
      float4 aa = rp[0], bb = rp[1];
      float bu = wup_r[j][0] * aa.x + wup_r[j][1] * aa.y + wup_r[j][2] * aa.z + wup_r[j][3] * aa.w +
                 wup_r[j][4] * bb.x + wup_r[j][5] * bb.y + wup_r[j][6] * bb.z + wup_r[j][7] * bb.w;
      prod *= bu;
    }
    int xg = x[n];
    float em = emt_l[xg * 32 + r];
    float nu = bfly8(pr * em * prod);
    if (s == 0) atomicAdd(&llb[n * 4 + g], __logf(nu));
  }
  __syncthreads();
  if (t < 32) atomicAdd(&out[t], llb[t]);
}

extern "C" void kernel_launch(void* const* d_in, const int* in_sizes, int n_in,
                              void* d_out, int out_size, void* d_ws, size_t ws_size,
                              hipStream_t stream) {
  const int* x = (const int*)d_in[0];
  const float* A = (const float*)d_in[1];
  const float* Bm = (const float*)d_in[2];
  const float* Pi = (const float*)d_in[3];
  float* ws = (float*)d_ws;
  float* WTD = ws + 0;       // 1024
  float* WUP = ws + 1024;    // 1024
  float* EMT = ws + 2048;    // 3200
  float* PIT = ws + 5248;    // 32
  float* RAT6 = ws + 5280;           // 32768*32
  float* RAT5 = RAT6 + 32768 * 32;   // 8192*32
  float* RAT4 = RAT5 + 8192 * 32;    // 2048*32
  float* RAT3 = RAT4 + 2048 * 32;    // 512*32   (total ~5.6 MB)
  float* out = (float*)d_out;

  hipMemsetAsync(d_out, 0, 32 * sizeof(float), stream);
  k_prep<<<1, 256, 0, stream>>>(A, Bm, Pi, WTD, WUP, EMT, PIT);
  k_sub6<<<1024, 256, 0, stream>>>(x, WTD, WUP, EMT, PIT, RAT6, out);
  k_up<5><<<1024, 256, 0, stream>>>(x, WTD, WUP, EMT, PIT, RAT6, RAT5, out);
  k_up<4><<<256, 256, 0, stream>>>(x, WTD, WUP, EMT, PIT, RAT5, RAT4, out);
  k_up<3><<<64, 256, 0, stream>>>(x, WTD, WUP, EMT, PIT, RAT4, RAT3, out);
  k_top<<<1, 256, 0, stream>>>(x, WTD, WUP, EMT, PIT, RAT3, out);
}

// Round 2
// 145.456 us; speedup vs baseline: 1.4113x; 1.4113x over previous
//
#include <hip/hip_runtime.h>

// HTMM: B_TREES=8, ARITY=4, DEPTH=8, C=8, M=100, NGEN=4
// Level offsets (cumsum of 8*4^l)
constexpr int OFFS1 = 8, OFFS2 = 40, OFFS3 = 168, OFFS4 = 680;
constexpr int OFFS5 = 2728, OFFS6 = 10920, OFFS7 = 43688, OFFS8 = 174760;

// lane mapping within a 32-lane group: r = g*8 + s (g = gen, s = state)
// WTD[(j*8+d)*32 + g*8+s] = P(child=s | parent=d, pos j, gen g)
// WUP[(j*8+c)*32 + g*8+d] = P(child=c | parent=d, pos j, gen g)   (transposed access)
// EMT[m*32 + g*8+c] = P(obs m | state c, gen g)
// PIT[g*8+c] = root prior

#define WB() __builtin_amdgcn_wave_barrier()

static __device__ __forceinline__ float bfly8(float v) {
  v += __shfl_xor(v, 1);
  v += __shfl_xor(v, 2);
  v += __shfl_xor(v, 4);
  return v;  // octet sum (all 8 lanes get it)
}

static __device__ __forceinline__ void ld8(const float* p, float pv[8]) {
  const float4* q = (const float4*)p;
  float4 a = q[0], b = q[1];
  pv[0] = a.x; pv[1] = a.y; pv[2] = a.z; pv[3] = a.w;
  pv[4] = b.x; pv[5] = b.y; pv[6] = b.z; pv[7] = b.w;
}

static __device__ __forceinline__ float dot8r(const float w[8], const float* p) {
  const float4* q = (const float4*)p;
  float4 a = q[0], b = q[1];
  return w[0] * a.x + w[1] * a.y + w[2] * a.z + w[3] * a.w +
         w[4] * b.x + w[5] * b.y + w[6] * b.z + w[7] * b.w;
}

// ---------------- k_prep: softmax tables ----------------
__global__ __launch_bounds__(256) void k_prep(const float* __restrict__ A,
                                              const float* __restrict__ Bm,
                                              const float* __restrict__ Pi,
                                              float* __restrict__ WTD,
                                              float* __restrict__ WUP,
                                              float* __restrict__ EMT,
                                              float* __restrict__ PIT) {
  int t = threadIdx.x;
  if (t < 128) {  // A: softmax over child state, column = (d,j,g)
    int d = t >> 4, j = (t >> 2) & 3, g = t & 3;
    float v[8], sum = 0.f;
#pragma unroll
    for (int s = 0; s < 8; s++) { v[s] = __expf(A[((s * 8 + d) * 4 + j) * 4 + g]); sum += v[s]; }
    float inv = 1.f / sum;
#pragma unroll
    for (int s = 0; s < 8; s++) {
      float p = v[s] * inv;
      WTD[((j * 8 + d) * 4 + g) * 8 + s] = p;
      WUP[((j * 8 + s) * 4 + g) * 8 + d] = p;
    }
  } else if (t < 160) {  // B: softmax over m, row = (c,g)
    int c = (t - 128) >> 2, g = (t - 128) & 3;
    float sum = 0.f;
    for (int m = 0; m < 100; m++) sum += __expf(Bm[(c * 100 + m) * 4 + g]);
    float inv = 1.f / sum;
    for (int m = 0; m < 100; m++) EMT[m * 32 + g * 8 + c] = __expf(Bm[(c * 100 + m) * 4 + g]) * inv;
  } else if (t < 164) {  // Pi
    int g = t - 160;
    float v[8], sum = 0.f;
#pragma unroll
    for (int s = 0; s < 8; s++) { v[s] = __expf(Pi[s * 4 + g]); sum += v[s]; }
    float inv = 1.f / sum;
#pragma unroll
    for (int s = 0; s < 8; s++) PIT[g * 8 + s] = v[s] * inv;
  }
}

// ---------------- k_sub5: fused levels 5..8 ----------------
// 8192 level-5 subtrees (85 nodes each), one per 32-lane group; 1024 blocks x 256.
__global__ __launch_bounds__(256, 4) void k_sub5(const int* __restrict__ x,
                                                 const float* __restrict__ WTD,
                                                 const float* __restrict__ WUP,
                                                 const float* __restrict__ EMT,
                                                 const float* __restrict__ PIT,
                                                 float* __restrict__ RAT5,
                                                 float* __restrict__ out) {
  __shared__ __align__(16) float wtd_l[1024];
  __shared__ __align__(16) float emt_l[3200];
  __shared__ __align__(16) float stash[8][13][32];  // per-group: 0-3 leaf, 4-7 L7, 8-11 L6, 12 bcast
  __shared__ float llb[4];
  int t = threadIdx.x;
  for (int i = t; i < 256; i += 256) ((float4*)wtd_l)[i] = ((const float4*)WTD)[i];
  for (int i = t; i < 800; i += 256) ((float4*)emt_l)[i] = ((const float4*)EMT)[i];
  if (t < 4) llb[t] = 0.f;
  __syncthreads();

  int r = t & 31, g = r >> 3, s = r & 7, grp = t >> 5;
  float* st = &stash[grp][0][0];
  float wtd_r[4][8], wup_r[4][8];
#pragma unroll
  for (int j = 0; j < 4; j++)
#pragma unroll
    for (int d = 0; d < 8; d++) {
      wtd_r[j][d] = wtd_l[(j * 8 + d) * 32 + r];
      wup_r[j][d] = WUP[(j * 8 + d) * 32 + r];
    }
  int n5 = blockIdx.x * 8 + grp;

  // prior path root -> level-5 node (5 matvecs, runtime positions -> wtd_l)
  float v5 = PIT[r];
#pragma unroll
  for (int k = 1; k <= 5; k++) {
    int j = (n5 >> (2 * (5 - k))) & 3;
    st[32 * 12 + r] = v5; WB();
    float pv[8]; ld8(st + 32 * 12 + g * 8, pv); WB();
    float nv = 0.f;
#pragma unroll
    for (int d = 0; d < 8; d++) nv += wtd_l[(j * 8 + d) * 32 + r] * pv[d];
    v5 = nv;
  }

  float acc = 0.f;
  float pv5[8];
  st[32 * 12 + r] = v5; WB(); ld8(st + 32 * 12 + g * 8, pv5); WB();

  const int4* x8v = (const int4*)(x + OFFS8 + n5 * 64);
  const int4* x7v = (const int4*)(x + OFFS7 + n5 * 16);
  int4 x6v = *(const int4*)(x + OFFS6 + n5 * 4);
  int x5s = x[OFFS5 + n5];

#pragma unroll 1
  for (int q6 = 0; q6 < 4; q6++) {
    int4 x7 = x7v[q6];
    const int* x7a = (const int*)&x7;
    // level-6 prior
    float u6 = 0.f;
#pragma unroll
    for (int d = 0; d < 8; d++) u6 += wtd_r[q6][d] * pv5[d];
    float pv6[8];
    st[32 * 12 + r] = u6; WB(); ld8(st + 32 * 12 + g * 8, pv6); WB();

#pragma unroll
    for (int q7 = 0; q7 < 4; q7++) {
      int4 xl = x8v[q6 * 4 + q7];
      const int* xla = (const int*)&xl;
      // level-7 prior
      float u7 = 0.f;
#pragma unroll
      for (int d = 0; d < 8; d++) u7 += wtd_r[q7][d] * pv6[d];
      float pv7[8];
      st[32 * 12 + r] = u7; WB(); ld8(st + 32 * 12 + g * 8, pv7); WB();
      // 4 leaves: prior, nu, ratio -> stash 0..3
#pragma unroll
      for (int j = 0; j < 4; j++) {
        float w = 0.f;
#pragma unroll
        for (int d = 0; d < 8; d++) w += wtd_r[j][d] * pv7[d];
        float em = emt_l[xla[j] * 32 + r];
        float nu = bfly8(w * em);
        acc += __logf(nu);
        st[32 * j + r] = em / nu;
      }
      WB();
      // level-7 upward
      float prod = 1.f;
#pragma unroll
      for (int j = 0; j < 4; j++) prod *= dot8r(wup_r[j], st + 32 * j + g * 8);
      WB();
      float em = emt_l[x7a[q7] * 32 + r];
      float nu = bfly8(u7 * em * prod);
      acc += __logf(nu);
      st[32 * (4 + q7) + r] = em * prod / nu;
    }
    WB();
    // level-6 upward
    float prod = 1.f;
#pragma unroll
    for (int j = 0; j < 4; j++) prod *= dot8r(wup_r[j], st + 32 * (4 + j) + g * 8);
    WB();
    float em = emt_l[((const int*)&x6v)[q6] * 32 + r];
    float nu = bfly8(u6 * em * prod);
    acc += __logf(nu);
    st[32 * (8 + q6) + r] = em * prod / nu;
  }
  WB();
  // level-5 upward -> RAT5
  float prod = 1.f;
#pragma unroll
  for (int j = 0; j < 4; j++) prod *= dot8r(wup_r[j], st + 32 * (8 + j) + g * 8);
  float em = emt_l[x5s * 32 + r];
  float nu = bfly8(v5 * em * prod);
  acc += __logf(nu);
  RAT5[n5 * 32 + r] = em * prod / nu;

  if (s == 0) atomicAdd(&llb[g], acc);
  __syncthreads();
  if (t < 4) atomicAdd(&out[(blockIdx.x >> 7) * 4 + t], llb[t]);  // 128 blocks/tree
}

// ---------------- k_tree: levels 4..0, one tree per block (8 blocks) ----------------
__global__ __launch_bounds__(256) void k_tree(const int* __restrict__ x,
                                              const float* __restrict__ WTD,
                                              const float* __restrict__ WUP,
                                              const float* __restrict__ EMT,
                                              const float* __restrict__ PIT,
                                              const float* __restrict__ RAT5,
                                              float* __restrict__ out) {
  __shared__ __align__(16) float wtd_l[1024];
  __shared__ __align__(16) float emt_l[3200];
  __shared__ __align__(16) float pri1[4][32], pri2[16][32], pri3[64][32];
  __shared__ __align__(16) float rat3[64][32], rat2[16][32], rat1[4][32];
  __shared__ __align__(16) float stash[8][4][32];
  __shared__ float llb[4];
  int t = threadIdx.x;
  for (int i = t; i < 256; i += 256) ((float4*)wtd_l)[i] = ((const float4*)WTD)[i];
  for (int i = t; i < 800; i += 256) ((float4*)emt_l)[i] = ((const float4*)EMT)[i];
  if (t < 4) llb[t] = 0.f;
  __syncthreads();
  int r = t & 31, g = r >> 3, s = r & 7, grp = t >> 5;
  int tree = blockIdx.x;
  float wup_r[4][8];
#pragma unroll
  for (int j = 0; j < 4; j++)
#pragma unroll
    for (int d = 0; d < 8; d++) wup_r[j][d] = WUP[(j * 8 + d) * 32 + r];
  float acc = 0.f;

  // TD level 1 (4 nodes)
  if (grp < 4) {
    float pv[8]; ld8(PIT + g * 8, pv);
    float v = 0.f;
#pragma unroll
    for (int d = 0; d < 8; d++) v += wtd_l[(grp * 8 + d) * 32 + r] * pv[d];
    pri1[grp][r] = v;
  }
  __syncthreads();
  // TD level 2 (16 nodes)
#pragma unroll
  for (int ii = 0; ii < 2; ii++) {
    int i2 = ii * 8 + grp, pa = i2 >> 2, j = i2 & 3;
    float pv[8]; ld8(&pri1[pa][g * 8], pv);
    float v = 0.f;
#pragma unroll
    for (int d = 0; d < 8; d++) v += wtd_l[(j * 8 + d) * 32 + r] * pv[d];
    pri2[i2][r] = v;
  }
  __syncthreads();
  // TD level 3 (64 nodes)
  for (int ii = 0; ii < 8; ii++) {
    int i3 = ii * 8 + grp, pa = i3 >> 2, j = i3 & 3;
    float pv[8]; ld8(&pri2[pa][g * 8], pv);
    float v = 0.f;
#pragma unroll
    for (int d = 0; d < 8; d++) v += wtd_l[(j * 8 + d) * 32 + r] * pv[d];
    pri3[i3][r] = v;
  }
  __syncthreads();
  // level 4 (prior + upward from RAT5) then level-3 upward
  for (int ii = 0; ii < 8; ii++) {
    int i3 = ii * 8 + grp;
    float pv3[8]; ld8(&pri3[i3][g * 8], pv3);
#pragma unroll
    for (int j4 = 0; j4 < 4; j4++) {
      int i4 = i3 * 4 + j4;
      float p4 = 0.f;
#pragma unroll
      for (int d = 0; d < 8; d++) p4 += wtd_l[(j4 * 8 + d) * 32 + r] * pv3[d];
      float prod = 1.f;
#pragma unroll
      for (int j = 0; j < 4; j++)
        prod *= dot8r(wup_r[j], RAT5 + ((tree * 256 + i4) * 4 + j) * 32 + g * 8);
      float em = emt_l[x[OFFS4 + tree * 256 + i4] * 32 + r];
      float nu = bfly8(p4 * em * prod);
      acc += __logf(nu);
      stash[grp][j4][r] = em * prod / nu;
    }
    WB();
    float prod = 1.f;
#pragma unroll
    for (int j = 0; j < 4; j++) prod *= dot8r(wup_r[j], &stash[grp][j][g * 8]);
    WB();
    float pr = pri3[i3][r];
    float em = emt_l[x[OFFS3 + tree * 64 + i3] * 32 + r];
    float nu = bfly8(pr * em * prod);
    acc += __logf(nu);
    rat3[i3][r] = em * prod / nu;
  }
  __syncthreads();
  // level 2 upward
#pragma unroll
  for (int ii = 0; ii < 2; ii++) {
    int i2 = ii * 8 + grp;
    float prod = 1.f;
#pragma unroll
    for (int j = 0; j < 4; j++) prod *= dot8r(wup_r[j], &rat3[i2 * 4 + j][g * 8]);
    float pr = pri2[i2][r];
    float em = emt_l[x[OFFS2 + tree * 16 + i2] * 32 + r];
    float nu = bfly8(pr * em * prod);
    acc += __logf(nu);
    rat2[i2][r] = em * prod / nu;
  }
  __syncthreads();
  // level 1 upward
  if (grp < 4) {
    float prod = 1.f;
#pragma unroll
    for (int j = 0; j < 4; j++) prod *= dot8r(wup_r[j], &rat2[grp * 4 + j][g * 8]);
    float pr = pri1[grp][r];
    float em = emt_l[x[OFFS1 + tree * 4 + grp] * 32 + r];
    float nu = bfly8(pr * em * prod);
    acc += __logf(nu);
    rat1[grp][r] = em * prod / nu;
  }
  __syncthreads();
  // level 0 (root)
  if (grp == 0) {
    float prod = 1.f;
#pragma unroll
    for (int j = 0; j < 4; j++) prod *= dot8r(wup_r[j], &rat1[j][g * 8]);
    float pr = PIT[r];
    float em = emt_l[x[tree] * 32 + r];
    float nu = bfly8(pr * em * prod);
    acc += __logf(nu);
  }
  if (s == 0) atomicAdd(&llb[g], acc);
  __syncthreads();
  if (t < 4) atomicAdd(&out[tree * 4 + t], llb[t]);
}

extern "C" void kernel_launch(void* const* d_in, const int* in_sizes, int n_in,
                              void* d_out, int out_size, void* d_ws, size_t ws_size,
                              hipStream_t stream) {
  const int* x = (const int*)d_in[0];
  const float* A = (const float*)d_in[1];
  const float* Bm = (const float*)d_in[2];
  const float* Pi = (const float*)d_in[3];
  float* ws = (float*)d_ws;
  float* WTD = ws + 0;     // 1024
  float* WUP = ws + 1024;  // 1024
  float* EMT = ws + 2048;  // 3200
  float* PIT = ws + 5248;  // 32
  float* RAT5 = ws + 5280; // 8192*32 = 1 MB
  float* out = (float*)d_out;

  hipMemsetAsync(d_out, 0, 32 * sizeof(float), stream);
  k_prep<<<1, 256, 0, stream>>>(A, Bm, Pi, WTD, WUP, EMT, PIT);
  k_sub5<<<1024, 256, 0, stream>>>(x, WTD, WUP, EMT, PIT, RAT5, out);
  k_tree<<<8, 256, 0, stream>>>(x, WTD, WUP, EMT, PIT, RAT5, out);
}